// Round 22
// baseline (63.080 us; speedup 1.0000x reference)
//
#include <hip/hip_runtime.h>
#include <hip/hip_bf16.h>

#define BB 8
#define CC 128
#define NN 4096
#define KCQ 32

typedef unsigned short u16;
typedef unsigned int u32;
typedef unsigned char u8;
typedef __bf16 bf16x8 __attribute__((ext_vector_type(8)));
typedef float f32x4 __attribute__((ext_vector_type(4)));
typedef long i64;
typedef long i64x2 __attribute__((ext_vector_type(2)));

typedef const __attribute__((address_space(1))) void gas_t;
typedef __attribute__((address_space(3))) void las_t;

__device__ __forceinline__ u16 f2bf(float f){
  u32 u = __builtin_bit_cast(u32, f);
  u32 r = u + 0x7FFFu + ((u >> 16) & 1u);
  return (u16)(r >> 16);
}
__device__ __forceinline__ u32 cvtpk(float lo, float hi){
  u32 r; asm("v_cvt_pk_bf16_f32 %0, %1, %2" : "=v"(r) : "v"(lo), "v"(hi)); return r;
}
__device__ __forceinline__ u32 pk_fp8x4(float a, float b, float c, float d){
  int v = 0;
  v = __builtin_amdgcn_cvt_pk_fp8_f32(a, b, v, false);
  v = __builtin_amdgcn_cvt_pk_fp8_f32(c, d, v, true);
  return (u32)v;
}
__device__ __forceinline__ void gload16(const void* g, void* l){
  __builtin_amdgcn_global_load_lds((gas_t*)g, (las_t*)l, 16, 0, 0);
}

// ---- kernel 0: weights f32 -> bf16 (Wq folds 1/sqrt(32)*log2(e) for exp2 softmax)
__global__ __launch_bounds__(256) void k_prep_w(const float* Wq, const float* Wk,
                                                const float* Wv, const float* Wo,
                                                u16* wsq, u16* wsk, u16* wsv, u16* wso){
  int i = blockIdx.x * 256 + threadIdx.x;
  const float SC = 0.2550350f; // log2(e)/sqrt(32)
  if (i < 4096)       wsq[i]        = f2bf(Wq[i] * SC);
  else if (i < 8192)  wsk[i-4096]   = f2bf(Wk[i-4096]);
  else if (i < 24576) wsv[i-8192]   = f2bf(Wv[i-8192]);
  else if (i < 40960) wso[i-24576]  = f2bf(Wo[i-24576]);
}

// ---- kernel 1: fused transpose+projection. 512 blocks x 512 thr. (R17 version)
__global__ __launch_bounds__(512) void k_projx(const float* x, const u16* wq, const u16* wk,
                                               const u16* wv, u16* Qm, u16* Km, u8* Vt8){
  __shared__ __align__(16) u16 xL[64*132];     // 16.9KB (vbuf overlays after frag loads)
  __shared__ __align__(16) u16 wvL[128*132];   // 33.8KB staged Wv
  int b = blockIdx.x >> 6, nb = (blockIdx.x & 63) * 64;
  int t = threadIdx.x;
  // x tile stage: 2048 f32x4 over [128c][64n]; gi -> row c = gi>>4, n4 = (gi&15)*4
  #pragma unroll
  for (int i = 0; i < 4; ++i){
    int gi = i*512 + t;
    int c = gi >> 4, n4 = (gi & 15) * 4;
    f32x4 v = *(const f32x4*)(x + ((size_t)b*CC + c)*NN + nb + n4);
    xL[(n4    )*132 + c] = f2bf(v[0]);
    xL[(n4 + 1)*132 + c] = f2bf(v[1]);
    xL[(n4 + 2)*132 + c] = f2bf(v[2]);
    xL[(n4 + 3)*132 + c] = f2bf(v[3]);
  }
  // Wv stage: 2048 uint4 (32KB bf16); gi -> row = gi>>4, u16 col = (gi&15)*8
  #pragma unroll
  for (int i = 0; i < 4; ++i){
    int gi = i*512 + t;
    int row = gi >> 4, c0 = (gi & 15) * 8;
    uint4 v = ((const uint4*)wv)[gi];
    uint2 lo; lo.x = v.x; lo.y = v.y;
    uint2 hi; hi.x = v.z; hi.y = v.w;
    *(uint2*)(wvL + row*132 + c0)     = lo;
    *(uint2*)(wvL + row*132 + c0 + 4) = hi;
  }
  __syncthreads();
  int w = t >> 6, l = t & 63, a = l & 15, g = l >> 4;
  int ns = w >> 1, half = w & 1;
  int n0 = nb + ns*16;
  bf16x8 xa[4];
  #pragma unroll
  for (int kc = 0; kc < 4; ++kc)
    xa[kc] = *(const bf16x8*)(xL + (ns*16 + a)*132 + kc*32 + g*8);
  __syncthreads();

  u32* vbuf = (u32*)xL;                  // [128 vchan][16 dwords], chunk ^ ((row>>1)&3)
  auto Vjob = [&](int vt){
    f32x4 acc = {0.f,0.f,0.f,0.f};
    #pragma unroll
    for (int kc = 0; kc < 4; ++kc){
      bf16x8 wa = *(const bf16x8*)(wvL + (vt*16 + a)*132 + kc*32 + g*8);
      acc = __builtin_amdgcn_mfma_f32_16x16x32_bf16(xa[kc], wa, acc, 0,0,0);
    }
    int row = vt*16 + a;
    vbuf[row*16 + ((ns ^ ((a>>1)&3)) << 2) + g] = pk_fp8x4(acc[0], acc[1], acc[2], acc[3]);
  };

  if (half == 0){
    #pragma unroll
    for (int qt = 0; qt < 2; ++qt){
      f32x4 accq = {0.f,0.f,0.f,0.f}, acck = {0.f,0.f,0.f,0.f};
      #pragma unroll
      for (int kc = 0; kc < 4; ++kc){
        bf16x8 wbq = ((const bf16x8*)(wq + (size_t)(qt*16 + a) * CC))[kc*4 + g];
        bf16x8 wbk = ((const bf16x8*)(wk + (size_t)(qt*16 + a) * CC))[kc*4 + g];
        accq = __builtin_amdgcn_mfma_f32_16x16x32_bf16(xa[kc], wbq, accq, 0,0,0);
        acck = __builtin_amdgcn_mfma_f32_16x16x32_bf16(xa[kc], wbk, acck, 0,0,0);
      }
      #pragma unroll
      for (int r = 0; r < 4; ++r){
        Qm[((size_t)b*NN + n0 + 4*g + r) * KCQ + qt*16 + a] = f2bf(accq[r]);
        Km[((size_t)b*NN + n0 + 4*g + r) * KCQ + qt*16 + a] = f2bf(acck[r]);
      }
    }
    Vjob(0); Vjob(1);
  } else {
    #pragma unroll
    for (int vt = 2; vt < 8; ++vt) Vjob(vt);
  }
  __syncthreads();
  // pi-permuted writeout: dest 16B chunk gg gets n-local {gg*8..+7} and {32+gg*8..+7}
  {
    int row = t >> 2, gg = t & 3, key = (row >> 1) & 3;
    const u32* vb = vbuf + row*16;
    auto rd = [&](int d){ return vb[(((d>>2)^key)<<2) + (d&3)]; };
    uint4 dd;
    dd.x = rd(2*gg);     dd.y = rd(2*gg+1);
    dd.z = rd(8+2*gg);   dd.w = rd(9+2*gg);
    *(uint4*)(Vt8 + ((size_t)b*CC + row)*NN + nb + gg*16) = dd;
  }
}

// ---- kernel 2: flash attention + fused output proj/residual. 512 blocks x 512 thr.
// R13/R17 loop + setprio(1) extended to the QK cluster (T5 on the phase-critical
// MFMA, not just PV). q-tile 64, 2 key-halves x 4 waves, V 3-slot staged at t+2,
// P 2-slot, 1 bar/kt, pi-interleaved P/V fp8 LDS.
__global__ __launch_bounds__(512, 4) void k_attn(const u16* Qm, const u16* Km,
                                                 const u8* Vt8, const u16* wso,
                                                 const float* x, const float* gamma,
                                                 float* out){
  __shared__ __align__(16) char smem[65536];
  // V slot s(0..2): s*16384 + h*8192 + vchan*64  [128][64B] fp8 pi, chunk ^ ((row>>1)&3)
  // P slot p(0..1): 49152 + p*8192 + h*4096 + q*64 [64][64B] fp8 pi, same swizzle
  // epilogue overlays: Cx [64][132] f32 @0; Ml [8][64] f32 @36864; Ol [64][128] bf16 @49152
  int bid = blockIdx.x;
  int b = bid & 7, qb = bid >> 3;      // one batch per XCD
  int t0 = threadIdx.x;
  int l = t0 & 63, a = l & 15, g = l >> 4;
  int w = t0 >> 6, h = w >> 2, wq = w & 3;
  int q0 = qb * 64;
  int kb0 = h * 2048;

  const u8* Vb = Vt8 + (size_t)b * CC * NN;

  bf16x8 qf[4];
  #pragma unroll
  for (int qs = 0; qs < 4; ++qs)
    qf[qs] = ((const bf16x8*)(Qm + ((size_t)b*NN + q0 + qs*16 + a) * KCQ))[g];
  const u16* kPtr = Km + ((size_t)b*NN + kb0 + wq*16 + a) * KCQ + g*8;

  f32x4 o[8];                          // [qs*2+st] = O^T[wq*32+st*16+4g+r][qs*16+a]
  #pragma unroll
  for (int i = 0; i < 8; ++i) o[i] = (f32x4){0.f,0.f,0.f,0.f};
  float ls[4] = {0.f, 0.f, 0.f, 0.f};

  int schk = (l&3) ^ ((l>>3)&3);
  const u8* vSrc = Vb + (size_t)(wq*32 + (l>>2))*NN + kb0 + (schk << 4);
  const int vOff = h*8192 + wq*2048 + l*16;
  auto stageV = [&](int t1, int sl){
    const u8* vs = vSrc + t1*64;
    char* vd = smem + sl*16384 + vOff;
    gload16(vs, vd);
    gload16(vs + (size_t)16*NN, vd + 1024);
  };

  const int cswz = (a >> 1) & 3;
  const int rc = (g ^ cswz) << 4;      // pi fragment chunk (read side)
  auto PV = [&](int ps, int vsl){
    const char* Vs = smem + vsl*16384 + h*8192;
    const char* Pr = smem + 49152 + ps*8192 + h*4096;
    __builtin_amdgcn_s_setprio(1);
    i64x2 vf0 = *(const i64x2*)(Vs + (wq*32 + a)*64 + rc);
    i64x2 vf1 = *(const i64x2*)(Vs + (wq*32 + 16 + a)*64 + rc);
    #pragma unroll
    for (int qs = 0; qs < 4; ++qs){
      i64x2 pf = *(const i64x2*)(Pr + (qs*16 + a)*64 + rc);
      o[qs*2  ] = __builtin_amdgcn_mfma_f32_16x16x32_fp8_fp8(vf0[0], pf[0], o[qs*2  ], 0,0,0);
      o[qs*2  ] = __builtin_amdgcn_mfma_f32_16x16x32_fp8_fp8(vf0[1], pf[1], o[qs*2  ], 0,0,0);
      o[qs*2+1] = __builtin_amdgcn_mfma_f32_16x16x32_fp8_fp8(vf1[0], pf[0], o[qs*2+1], 0,0,0);
      o[qs*2+1] = __builtin_amdgcn_mfma_f32_16x16x32_fp8_fp8(vf1[1], pf[1], o[qs*2+1], 0,0,0);
    }
    __builtin_amdgcn_s_setprio(0);
  };

  // P write offset, pi layout: k0 = wq*16+4g -> gg=(wq&1)*2+(g>>1), kk=wq>>1, j=(g&1)*4
  const int ppos = (((((wq&1)<<1) | (g>>1)) ^ cswz) << 4) | ((wq>>1) << 3) | ((g&1) << 2);
  auto SM = [&](const f32x4* sv, char* Pw){
    #pragma unroll
    for (int qs = 0; qs < 4; ++qs){
      float p0 = __builtin_amdgcn_exp2f(sv[qs][0]);
      float p1 = __builtin_amdgcn_exp2f(sv[qs][1]);
      float p2 = __builtin_amdgcn_exp2f(sv[qs][2]);
      float p3 = __builtin_amdgcn_exp2f(sv[qs][3]);
      ls[qs] += (p0 + p1) + (p2 + p3);
      *(u32*)(Pw + (qs*16 + a)*64 + ppos) = pk_fp8x4(p0, p1, p2, p3);
    }
  };

  char* PwBase = smem + 49152 + h*4096;

  // prologue: K(0),K(1) loads first; V(0),V(1) stages; QK(0)+SM(0)->slot0; vmcnt(2); bar
  bf16x8 kfC = *(const bf16x8*)(kPtr);               // K(0)
  bf16x8 kfN = *(const bf16x8*)(kPtr + 2048);        // K(1)
  stageV(0, 0);
  stageV(1, 1);
  {
    f32x4 sv[4];
    __builtin_amdgcn_s_setprio(1);
    #pragma unroll
    for (int qs = 0; qs < 4; ++qs){
      f32x4 z = {0.f,0.f,0.f,0.f};
      sv[qs] = __builtin_amdgcn_mfma_f32_16x16x32_bf16(kfC, qf[qs], z, 0,0,0);
    }
    __builtin_amdgcn_s_setprio(0);
    SM(sv, PwBase);                                  // P slot 0
  }
  asm volatile("s_waitcnt vmcnt(2) lgkmcnt(0)" ::: "memory");
  __builtin_amdgcn_s_barrier();

  int vR = 0;                          // V slot of tile t (t%3)
  for (int t = 0; t < 31; ++t){
    // QK(t+1): register-only inputs, priority-boosted (phase critical path)
    f32x4 sv[4];
    __builtin_amdgcn_s_setprio(1);
    #pragma unroll
    for (int qs = 0; qs < 4; ++qs){
      f32x4 z = {0.f,0.f,0.f,0.f};
      sv[qs] = __builtin_amdgcn_mfma_f32_16x16x32_bf16(kfN, qf[qs], z, 0,0,0);
    }
    __builtin_amdgcn_s_setprio(0);
    // PV(t): P slot t&1, V slot t%3 — overlaps SM below
    PV(t & 1, vR);
    // softmax(t+1) -> P slot (t+1)&1
    SM(sv, PwBase + ((t+1)&1)*8192);
    // stage V(t+2), prefetch K(t+2)
    if (t < 30){
      kfC = *(const bf16x8*)(kPtr + (size_t)(t+2)*2048);
      int sl = vR >= 1 ? vR - 1 : 2;   // (t+2)%3
      stageV(t+2, sl);
      asm volatile("s_waitcnt vmcnt(3) lgkmcnt(0)" ::: "memory");  // V(t+1)+older landed
    } else {
      asm volatile("s_waitcnt vmcnt(0) lgkmcnt(0)" ::: "memory");
    }
    __builtin_amdgcn_s_barrier();
    kfN = kfC;
    vR = (vR == 2) ? 0 : vR + 1;
  }
  PV(1, vR);                           // tail: PV(31), P slot 1, V slot 31%3=1

  // ---- fused epilogue ----
  #pragma unroll
  for (int qs = 0; qs < 4; ++qs){
    ls[qs] += __shfl_xor(ls[qs], 16);
    ls[qs] += __shfl_xor(ls[qs], 32);
  }
  float* Ml = (float*)(smem + 36864);   // V slot 2 region (dead)
  if (l < 16){
    #pragma unroll
    for (int qs = 0; qs < 4; ++qs) Ml[w*64 + qs*16 + l] = ls[qs];
  }
  float* Cx = (float*)smem;             // V slots 0-1 (dead after X1)
  __syncthreads();                      // X1
  if (h == 1){
    #pragma unroll
    for (int i = 0; i < 8; ++i){
      int qs = i >> 1, st = i & 1;
      *(f32x4*)(Cx + (qs*16 + a)*132 + wq*32 + st*16 + 4*g) = o[i];
    }
  }
  __syncthreads();                      // X2
  u16* Ol = (u16*)(smem + 49152);       // [64q][128c] bf16, chunk16 ^ (q&7)
  if (h == 0){
    #pragma unroll
    for (int qs = 0; qs < 4; ++qs){
      float lsum = 0.f;
      #pragma unroll
      for (int ww = 0; ww < 8; ++ww) lsum += Ml[ww*64 + qs*16 + a];
      float inv = 1.f / lsum;
      #pragma unroll
      for (int st = 0; st < 2; ++st){
        f32x4 oc = o[qs*2 + st];
        const float* cx = Cx + (qs*16 + a)*132 + wq*32 + st*16 + 4*g;
        uint2 pk;
        pk.x = cvtpk((oc[0] + cx[0]) * inv, (oc[1] + cx[1]) * inv);
        pk.y = cvtpk((oc[2] + cx[2]) * inv, (oc[3] + cx[3]) * inv);
        int chunk = (wq*4 + st*2 + (g>>1)) ^ (a & 7);   // c0 = wq*32+st*16+4g
        *(uint2*)((char*)Ol + (qs*16 + a)*256 + chunk*16 + (g&1)*8) = pk;
      }
    }
  }
  __syncthreads();                      // X3
  // out-GEMM: wave w -> out rows [w*16,+16), all 64 q. out = x + gm * O@Wo^T
  float gm = gamma[0];
  f32x4 acc2[4];
  #pragma unroll
  for (int qs = 0; qs < 4; ++qs) acc2[qs] = (f32x4){0.f,0.f,0.f,0.f};
  #pragma unroll
  for (int kc = 0; kc < 4; ++kc){
    bf16x8 wof = *(const bf16x8*)(wso + (size_t)(w*16 + a)*CC + kc*32 + g*8);
    #pragma unroll
    for (int qs = 0; qs < 4; ++qs){
      int chunk = (kc*4 + g) ^ (a & 7);
      bf16x8 of = *(const bf16x8*)((const char*)Ol + (qs*16 + a)*256 + chunk*16);
      acc2[qs] = __builtin_amdgcn_mfma_f32_16x16x32_bf16(wof, of, acc2[qs], 0,0,0);
    }
  }
  #pragma unroll
  for (int qs = 0; qs < 4; ++qs){
    #pragma unroll
    for (int r = 0; r < 4; ++r){
      size_t idx = ((size_t)b*CC + w*16 + 4*g + r)*NN + q0 + qs*16 + a;
      out[idx] = x[idx] + gm * acc2[qs][r];
    }
  }
}

extern "C" void kernel_launch(void* const* d_in, const int* in_sizes, int n_in,
                              void* d_out, int out_size, void* d_ws, size_t ws_size,
                              hipStream_t stream) {
  const float* x     = (const float*)d_in[0];
  const float* Wq    = (const float*)d_in[1];
  const float* Wk    = (const float*)d_in[2];
  const float* Wv    = (const float*)d_in[3];
  const float* Wo    = (const float*)d_in[4];
  const float* gamma = (const float*)d_in[5];
  float* out = (float*)d_out;

  u16* wsq = (u16*)d_ws;
  u16* wsk = wsq + 4096;
  u16* wsv = wsk + 4096;
  u16* wso = wsv + 16384;
  u16* Qm  = wso + 16384;
  u16* Km  = Qm + (size_t)BB*NN*KCQ;
  u8*  Vt8 = (u8*)(Km + (size_t)BB*NN*KCQ);

  hipLaunchKernelGGL(k_prep_w, dim3(160), dim3(256), 0, stream, Wq, Wk, Wv, Wo, wsq, wsk, wsv, wso);
  hipLaunchKernelGGL(k_projx,  dim3(512), dim3(512), 0, stream, x, wsq, wsk, wsv, Qm, Km, Vt8);
  hipLaunchKernelGGL(k_attn,   dim3(512), dim3(512), 0, stream, Qm, Km, Vt8, wso, x, gamma, out);
}

// Round 23
// 61.437 us; speedup vs baseline: 1.0267x; 1.0267x over previous
//
#include <hip/hip_runtime.h>
#include <hip/hip_bf16.h>

#define BB 8
#define CC 128
#define NN 4096
#define KCQ 32

typedef unsigned short u16;
typedef unsigned int u32;
typedef unsigned char u8;
typedef __bf16 bf16x8 __attribute__((ext_vector_type(8)));
typedef float f32x4 __attribute__((ext_vector_type(4)));
typedef long i64;
typedef long i64x2 __attribute__((ext_vector_type(2)));

typedef const __attribute__((address_space(1))) void gas_t;
typedef __attribute__((address_space(3))) void las_t;

__device__ __forceinline__ u16 f2bf(float f){
  u32 u = __builtin_bit_cast(u32, f);
  u32 r = u + 0x7FFFu + ((u >> 16) & 1u);
  return (u16)(r >> 16);
}
__device__ __forceinline__ u32 cvtpk(float lo, float hi){
  u32 r; asm("v_cvt_pk_bf16_f32 %0, %1, %2" : "=v"(r) : "v"(lo), "v"(hi)); return r;
}
__device__ __forceinline__ u32 pk_fp8x4(float a, float b, float c, float d){
  int v = 0;
  v = __builtin_amdgcn_cvt_pk_fp8_f32(a, b, v, false);
  v = __builtin_amdgcn_cvt_pk_fp8_f32(c, d, v, true);
  return (u32)v;
}
__device__ __forceinline__ void gload16(const void* g, void* l){
  __builtin_amdgcn_global_load_lds((gas_t*)g, (las_t*)l, 16, 0, 0);
}

// ---- kernel 0: weights f32 -> bf16 (Wq folds 1/sqrt(32)*log2(e) for exp2 softmax)
__global__ __launch_bounds__(256) void k_prep_w(const float* Wq, const float* Wk,
                                                const float* Wv, const float* Wo,
                                                u16* wsq, u16* wsk, u16* wsv, u16* wso){
  int i = blockIdx.x * 256 + threadIdx.x;
  const float SC = 0.2550350f; // log2(e)/sqrt(32)
  if (i < 4096)       wsq[i]        = f2bf(Wq[i] * SC);
  else if (i < 8192)  wsk[i-4096]   = f2bf(Wk[i-4096]);
  else if (i < 24576) wsv[i-8192]   = f2bf(Wv[i-8192]);
  else if (i < 40960) wso[i-24576]  = f2bf(Wo[i-24576]);
}

// ---- kernel 1: fused transpose+projection. 512 blocks x 512 thr.
// Staging coalesced: x via 4x f32x4/thread, Wv via 4x uint4/thread + 2x b64 LDS writes.
// V stored fp8, k-INTERLEAVED within each 64-n group: pos(k) = gg*16 + kk*8 + j
// for k = kk*32 + gg*8 + j  -> attn reads each PV fragment pair as one b128.
__global__ __launch_bounds__(512) void k_projx(const float* x, const u16* wq, const u16* wk,
                                               const u16* wv, u16* Qm, u16* Km, u8* Vt8){
  __shared__ __align__(16) u16 xL[64*132];     // 16.9KB (vbuf overlays after frag loads)
  __shared__ __align__(16) u16 wvL[128*132];   // 33.8KB staged Wv
  int b = blockIdx.x >> 6, nb = (blockIdx.x & 63) * 64;
  int t = threadIdx.x;
  // x tile stage: 2048 f32x4 over [128c][64n]; gi -> row c = gi>>4, n4 = (gi&15)*4
  #pragma unroll
  for (int i = 0; i < 4; ++i){
    int gi = i*512 + t;
    int c = gi >> 4, n4 = (gi & 15) * 4;
    f32x4 v = *(const f32x4*)(x + ((size_t)b*CC + c)*NN + nb + n4);
    xL[(n4    )*132 + c] = f2bf(v[0]);
    xL[(n4 + 1)*132 + c] = f2bf(v[1]);
    xL[(n4 + 2)*132 + c] = f2bf(v[2]);
    xL[(n4 + 3)*132 + c] = f2bf(v[3]);
  }
  // Wv stage: 2048 uint4 (32KB bf16); gi -> row = gi>>4, u16 col = (gi&15)*8
  #pragma unroll
  for (int i = 0; i < 4; ++i){
    int gi = i*512 + t;
    int row = gi >> 4, c0 = (gi & 15) * 8;
    uint4 v = ((const uint4*)wv)[gi];
    uint2 lo; lo.x = v.x; lo.y = v.y;
    uint2 hi; hi.x = v.z; hi.y = v.w;
    *(uint2*)(wvL + row*132 + c0)     = lo;
    *(uint2*)(wvL + row*132 + c0 + 4) = hi;
  }
  __syncthreads();
  int w = t >> 6, l = t & 63, a = l & 15, g = l >> 4;
  int ns = w >> 1, half = w & 1;
  int n0 = nb + ns*16;
  bf16x8 xa[4];
  #pragma unroll
  for (int kc = 0; kc < 4; ++kc)
    xa[kc] = *(const bf16x8*)(xL + (ns*16 + a)*132 + kc*32 + g*8);
  __syncthreads();

  u32* vbuf = (u32*)xL;                  // [128 vchan][16 dwords], chunk ^ ((row>>1)&3)
  auto Vjob = [&](int vt){
    f32x4 acc = {0.f,0.f,0.f,0.f};
    #pragma unroll
    for (int kc = 0; kc < 4; ++kc){
      bf16x8 wa = *(const bf16x8*)(wvL + (vt*16 + a)*132 + kc*32 + g*8);
      acc = __builtin_amdgcn_mfma_f32_16x16x32_bf16(xa[kc], wa, acc, 0,0,0);
    }
    int row = vt*16 + a;
    vbuf[row*16 + ((ns ^ ((a>>1)&3)) << 2) + g] = pk_fp8x4(acc[0], acc[1], acc[2], acc[3]);
  };

  if (half == 0){
    #pragma unroll
    for (int qt = 0; qt < 2; ++qt){
      f32x4 accq = {0.f,0.f,0.f,0.f}, acck = {0.f,0.f,0.f,0.f};
      #pragma unroll
      for (int kc = 0; kc < 4; ++kc){
        bf16x8 wbq = ((const bf16x8*)(wq + (size_t)(qt*16 + a) * CC))[kc*4 + g];
        bf16x8 wbk = ((const bf16x8*)(wk + (size_t)(qt*16 + a) * CC))[kc*4 + g];
        accq = __builtin_amdgcn_mfma_f32_16x16x32_bf16(xa[kc], wbq, accq, 0,0,0);
        acck = __builtin_amdgcn_mfma_f32_16x16x32_bf16(xa[kc], wbk, acck, 0,0,0);
      }
      #pragma unroll
      for (int r = 0; r < 4; ++r){
        Qm[((size_t)b*NN + n0 + 4*g + r) * KCQ + qt*16 + a] = f2bf(accq[r]);
        Km[((size_t)b*NN + n0 + 4*g + r) * KCQ + qt*16 + a] = f2bf(acck[r]);
      }
    }
    Vjob(0); Vjob(1);
  } else {
    #pragma unroll
    for (int vt = 2; vt < 8; ++vt) Vjob(vt);
  }
  __syncthreads();
  // pi-permuted writeout: dest 16B chunk gg gets n-local {gg*8..+7} and {32+gg*8..+7}
  {
    int row = t >> 2, gg = t & 3, key = (row >> 1) & 3;
    const u32* vb = vbuf + row*16;
    auto rd = [&](int d){ return vb[(((d>>2)^key)<<2) + (d&3)]; };
    uint4 dd;
    dd.x = rd(2*gg);     dd.y = rd(2*gg+1);
    dd.z = rd(8+2*gg);   dd.w = rd(9+2*gg);
    *(uint4*)(Vt8 + ((size_t)b*CC + row)*NN + nb + gg*16) = dd;
  }
}

// ---- kernel 2: flash attention + fused output proj/residual. 512 blocks x 512 thr.
// (R13/R17 loop — best measured; setprio on PV only. q-tile 64, 2 key-halves x
// 4 waves, V 3-slot staged at t+2, P 2-slot, 1 bar/kt, pipeline QK(t+1) -> PV(t)
// -> SM(t+1) -> K(t+2)+stageV(t+2) -> vmcnt(3)+bar; pi-interleaved P/V fp8 LDS.)
__global__ __launch_bounds__(512, 4) void k_attn(const u16* Qm, const u16* Km,
                                                 const u8* Vt8, const u16* wso,
                                                 const float* x, const float* gamma,
                                                 float* out){
  __shared__ __align__(16) char smem[65536];
  // V slot s(0..2): s*16384 + h*8192 + vchan*64  [128][64B] fp8 pi, chunk ^ ((row>>1)&3)
  // P slot p(0..1): 49152 + p*8192 + h*4096 + q*64 [64][64B] fp8 pi, same swizzle
  // epilogue overlays: Cx [64][132] f32 @0; Ml [8][64] f32 @36864; Ol [64][128] bf16 @49152
  int bid = blockIdx.x;
  int b = bid & 7, qb = bid >> 3;      // one batch per XCD
  int t0 = threadIdx.x;
  int l = t0 & 63, a = l & 15, g = l >> 4;
  int w = t0 >> 6, h = w >> 2, wq = w & 3;
  int q0 = qb * 64;
  int kb0 = h * 2048;

  const u8* Vb = Vt8 + (size_t)b * CC * NN;

  bf16x8 qf[4];
  #pragma unroll
  for (int qs = 0; qs < 4; ++qs)
    qf[qs] = ((const bf16x8*)(Qm + ((size_t)b*NN + q0 + qs*16 + a) * KCQ))[g];
  const u16* kPtr = Km + ((size_t)b*NN + kb0 + wq*16 + a) * KCQ + g*8;

  f32x4 o[8];                          // [qs*2+st] = O^T[wq*32+st*16+4g+r][qs*16+a]
  #pragma unroll
  for (int i = 0; i < 8; ++i) o[i] = (f32x4){0.f,0.f,0.f,0.f};
  float ls[4] = {0.f, 0.f, 0.f, 0.f};

  int schk = (l&3) ^ ((l>>3)&3);
  const u8* vSrc = Vb + (size_t)(wq*32 + (l>>2))*NN + kb0 + (schk << 4);
  const int vOff = h*8192 + wq*2048 + l*16;
  auto stageV = [&](int t1, int sl){
    const u8* vs = vSrc + t1*64;
    char* vd = smem + sl*16384 + vOff;
    gload16(vs, vd);
    gload16(vs + (size_t)16*NN, vd + 1024);
  };

  const int cswz = (a >> 1) & 3;
  const int rc = (g ^ cswz) << 4;      // pi fragment chunk (read side)
  auto PV = [&](int ps, int vsl){
    const char* Vs = smem + vsl*16384 + h*8192;
    const char* Pr = smem + 49152 + ps*8192 + h*4096;
    __builtin_amdgcn_s_setprio(1);
    i64x2 vf0 = *(const i64x2*)(Vs + (wq*32 + a)*64 + rc);
    i64x2 vf1 = *(const i64x2*)(Vs + (wq*32 + 16 + a)*64 + rc);
    #pragma unroll
    for (int qs = 0; qs < 4; ++qs){
      i64x2 pf = *(const i64x2*)(Pr + (qs*16 + a)*64 + rc);
      o[qs*2  ] = __builtin_amdgcn_mfma_f32_16x16x32_fp8_fp8(vf0[0], pf[0], o[qs*2  ], 0,0,0);
      o[qs*2  ] = __builtin_amdgcn_mfma_f32_16x16x32_fp8_fp8(vf0[1], pf[1], o[qs*2  ], 0,0,0);
      o[qs*2+1] = __builtin_amdgcn_mfma_f32_16x16x32_fp8_fp8(vf1[0], pf[0], o[qs*2+1], 0,0,0);
      o[qs*2+1] = __builtin_amdgcn_mfma_f32_16x16x32_fp8_fp8(vf1[1], pf[1], o[qs*2+1], 0,0,0);
    }
    __builtin_amdgcn_s_setprio(0);
  };

  // P write offset, pi layout: k0 = wq*16+4g -> gg=(wq&1)*2+(g>>1), kk=wq>>1, j=(g&1)*4
  const int ppos = (((((wq&1)<<1) | (g>>1)) ^ cswz) << 4) | ((wq>>1) << 3) | ((g&1) << 2);
  auto SM = [&](const f32x4* sv, char* Pw){
    #pragma unroll
    for (int qs = 0; qs < 4; ++qs){
      float p0 = __builtin_amdgcn_exp2f(sv[qs][0]);
      float p1 = __builtin_amdgcn_exp2f(sv[qs][1]);
      float p2 = __builtin_amdgcn_exp2f(sv[qs][2]);
      float p3 = __builtin_amdgcn_exp2f(sv[qs][3]);
      ls[qs] += (p0 + p1) + (p2 + p3);
      *(u32*)(Pw + (qs*16 + a)*64 + ppos) = pk_fp8x4(p0, p1, p2, p3);
    }
  };

  char* PwBase = smem + 49152 + h*4096;

  // prologue: K(0),K(1) loads first; V(0),V(1) stages; QK(0)+SM(0)->slot0; vmcnt(2); bar
  bf16x8 kfC = *(const bf16x8*)(kPtr);               // K(0)
  bf16x8 kfN = *(const bf16x8*)(kPtr + 2048);        // K(1)
  stageV(0, 0);
  stageV(1, 1);
  {
    f32x4 sv[4];
    #pragma unroll
    for (int qs = 0; qs < 4; ++qs){
      f32x4 z = {0.f,0.f,0.f,0.f};
      sv[qs] = __builtin_amdgcn_mfma_f32_16x16x32_bf16(kfC, qf[qs], z, 0,0,0);
    }
    SM(sv, PwBase);                                  // P slot 0
  }
  asm volatile("s_waitcnt vmcnt(2) lgkmcnt(0)" ::: "memory");
  __builtin_amdgcn_s_barrier();

  int vR = 0;                          // V slot of tile t (t%3)
  for (int t = 0; t < 31; ++t){
    // QK(t+1): register-only inputs
    f32x4 sv[4];
    #pragma unroll
    for (int qs = 0; qs < 4; ++qs){
      f32x4 z = {0.f,0.f,0.f,0.f};
      sv[qs] = __builtin_amdgcn_mfma_f32_16x16x32_bf16(kfN, qf[qs], z, 0,0,0);
    }
    // PV(t): P slot t&1, V slot t%3 — overlaps SM below
    PV(t & 1, vR);
    // softmax(t+1) -> P slot (t+1)&1
    SM(sv, PwBase + ((t+1)&1)*8192);
    // stage V(t+2), prefetch K(t+2)
    if (t < 30){
      kfC = *(const bf16x8*)(kPtr + (size_t)(t+2)*2048);
      int sl = vR >= 1 ? vR - 1 : 2;   // (t+2)%3
      stageV(t+2, sl);
      asm volatile("s_waitcnt vmcnt(3) lgkmcnt(0)" ::: "memory");  // V(t+1)+older landed
    } else {
      asm volatile("s_waitcnt vmcnt(0) lgkmcnt(0)" ::: "memory");
    }
    __builtin_amdgcn_s_barrier();
    kfN = kfC;
    vR = (vR == 2) ? 0 : vR + 1;
  }
  PV(1, vR);                           // tail: PV(31), P slot 1, V slot 31%3=1

  // ---- fused epilogue ----
  #pragma unroll
  for (int qs = 0; qs < 4; ++qs){
    ls[qs] += __shfl_xor(ls[qs], 16);
    ls[qs] += __shfl_xor(ls[qs], 32);
  }
  float* Ml = (float*)(smem + 36864);   // V slot 2 region (dead)
  if (l < 16){
    #pragma unroll
    for (int qs = 0; qs < 4; ++qs) Ml[w*64 + qs*16 + l] = ls[qs];
  }
  float* Cx = (float*)smem;             // V slots 0-1 (dead after X1)
  __syncthreads();                      // X1
  if (h == 1){
    #pragma unroll
    for (int i = 0; i < 8; ++i){
      int qs = i >> 1, st = i & 1;
      *(f32x4*)(Cx + (qs*16 + a)*132 + wq*32 + st*16 + 4*g) = o[i];
    }
  }
  __syncthreads();                      // X2
  u16* Ol = (u16*)(smem + 49152);       // [64q][128c] bf16, chunk16 ^ (q&7)
  if (h == 0){
    #pragma unroll
    for (int qs = 0; qs < 4; ++qs){
      float lsum = 0.f;
      #pragma unroll
      for (int ww = 0; ww < 8; ++ww) lsum += Ml[ww*64 + qs*16 + a];
      float inv = 1.f / lsum;
      #pragma unroll
      for (int st = 0; st < 2; ++st){
        f32x4 oc = o[qs*2 + st];
        const float* cx = Cx + (qs*16 + a)*132 + wq*32 + st*16 + 4*g;
        uint2 pk;
        pk.x = cvtpk((oc[0] + cx[0]) * inv, (oc[1] + cx[1]) * inv);
        pk.y = cvtpk((oc[2] + cx[2]) * inv, (oc[3] + cx[3]) * inv);
        int chunk = (wq*4 + st*2 + (g>>1)) ^ (a & 7);   // c0 = wq*32+st*16+4g
        *(uint2*)((char*)Ol + (qs*16 + a)*256 + chunk*16 + (g&1)*8) = pk;
      }
    }
  }
  __syncthreads();                      // X3
  // out-GEMM: wave w -> out rows [w*16,+16), all 64 q. out = x + gm * O@Wo^T
  float gm = gamma[0];
  f32x4 acc2[4];
  #pragma unroll
  for (int qs = 0; qs < 4; ++qs) acc2[qs] = (f32x4){0.f,0.f,0.f,0.f};
  #pragma unroll
  for (int kc = 0; kc < 4; ++kc){
    bf16x8 wof = *(const bf16x8*)(wso + (size_t)(w*16 + a)*CC + kc*32 + g*8);
    #pragma unroll
    for (int qs = 0; qs < 4; ++qs){
      int chunk = (kc*4 + g) ^ (a & 7);
      bf16x8 of = *(const bf16x8*)((const char*)Ol + (qs*16 + a)*256 + chunk*16);
      acc2[qs] = __builtin_amdgcn_mfma_f32_16x16x32_bf16(wof, of, acc2[qs], 0,0,0);
    }
  }
  #pragma unroll
  for (int qs = 0; qs < 4; ++qs){
    #pragma unroll
    for (int r = 0; r < 4; ++r){
      size_t idx = ((size_t)b*CC + w*16 + 4*g + r)*NN + q0 + qs*16 + a;
      out[idx] = x[idx] + gm * acc2[qs][r];
    }
  }
}

extern "C" void kernel_launch(void* const* d_in, const int* in_sizes, int n_in,
                              void* d_out, int out_size, void* d_ws, size_t ws_size,
                              hipStream_t stream) {
  const float* x     = (const float*)d_in[0];
  const float* Wq    = (const float*)d_in[1];
  const float* Wk    = (const float*)d_in[2];
  const float* Wv    = (const float*)d_in[3];
  const float* Wo    = (const float*)d_in[4];
  const float* gamma = (const float*)d_in[5];
  float* out = (float*)d_out;

  u16* wsq = (u16*)d_ws;
  u16* wsk = wsq + 4096;
  u16* wsv = wsk + 4096;
  u16* wso = wsv + 16384;
  u16* Qm  = wso + 16384;
  u16* Km  = Qm + (size_t)BB*NN*KCQ;
  u8*  Vt8 = (u8*)(Km + (size_t)BB*NN*KCQ);

  hipLaunchKernelGGL(k_prep_w, dim3(160), dim3(256), 0, stream, Wq, Wk, Wv, Wo, wsq, wsk, wsv, wso);
  hipLaunchKernelGGL(k_projx,  dim3(512), dim3(512), 0, stream, x, wsq, wsk, wsv, Qm, Km, Vt8);
  hipLaunchKernelGGL(k_attn,   dim3(512), dim3(512), 0, stream, Qm, Km, Vt8, wso, x, gamma, out);
}